// Round 1
// baseline (8460.394 us; speedup 1.0000x reference)
//
#include <hip/hip_runtime.h>
#include <math.h>

#define NNODES 40000
#define NEDGES 640000

__device__ __forceinline__ float4 ld4(const float* p) { return *(const float4*)p; }

// ---------------- Stage 1: s' = s @ W1s/sqrt(32); v' = einsum(v, W1v)/sqrt(32)
// A[n*128 + c]: c<32 -> s'[c]; c>=32 -> v'[w][i] at 32 + w*3 + i
__global__ void k1_stage1(const float* __restrict__ node_input,
                          const float* __restrict__ w1s,
                          const float* __restrict__ w1v,
                          float* __restrict__ A) {
  const float scale = 0.17677669529663687f; // 1/sqrt(32)
  int stride = gridDim.x * blockDim.x;
  for (int idx = blockIdx.x * blockDim.x + threadIdx.x; idx < NNODES * 128; idx += stride) {
    int n = idx >> 7;
    int c = idx & 127;
    const float* row = node_input + n * 128;
    float acc = 0.f;
    if (c < 32) {
      #pragma unroll
      for (int u = 0; u < 32; ++u)
        acc = fmaf(row[u], w1s[u * 32 + c], acc);
    } else {
      int cc = c - 32;
      int w = cc / 3;
      int i = cc - w * 3;
      #pragma unroll
      for (int u = 0; u < 32; ++u)
        acc = fmaf(row[32 + u * 3 + i], w1v[u * 32 + w], acc);
    }
    A[idx] = acc * scale;
  }
}

// ---------------- Edge kernel: MLP weights + tensor product + atomic scatter
// ACC row layout (256 floats per node):
//   [0..31]    sum mid_s0[u]
//   [32..63]   sum mid_s1[u]
//   [64..159]  sum mid_v0[u][i] at 64 + u*3 + i
//   [160..255] sum mid_v1[u][i] at 160 + u*3 + i
__global__ __launch_bounds__(256) void k2_edges(
    const float* __restrict__ A,
    const int* __restrict__ edge_src,
    const int* __restrict__ edge_dst,
    const float* __restrict__ edge_attr,
    const float* __restrict__ edge_scalars,
    const float* __restrict__ fc_w1,
    const float* __restrict__ fc_w2,
    float* __restrict__ ACC) {
  const float INV_SQRT8 = 0.35355339059327373f;
  const float H_SCALE   = 1.6791767923989418f / 8.0f; // SILU_NORM / sqrt(64)
  const float INV_SQRT3 = 0.57735026918962576f;

  int e = blockIdx.x * blockDim.x + threadIdx.x;
  if (e >= NEDGES) return;

  // edge scalars (8), pre-scaled by 1/sqrt(8)
  float4 s0 = ld4(edge_scalars + e * 8);
  float4 s1 = ld4(edge_scalars + e * 8 + 4);
  float es8[8] = {s0.x * INV_SQRT8, s0.y * INV_SQRT8, s0.z * INV_SQRT8, s0.w * INV_SQRT8,
                  s1.x * INV_SQRT8, s1.y * INV_SQRT8, s1.z * INV_SQRT8, s1.w * INV_SQRT8};

  // h[j] = silu(es8 . W1[:,j]) * SILU_NORM/8   (the /8 folds the W2 1/sqrt(64))
  float h[64];
  #pragma unroll
  for (int j = 0; j < 64; ++j) {
    float x = 0.f;
    #pragma unroll
    for (int i = 0; i < 8; ++i)
      x = fmaf(es8[i], fc_w1[i * 64 + j], x);  // uniform address -> s_load
    h[j] = (x * H_SCALE) / (1.0f + __expf(-x));
  }

  int src = edge_src[e];
  int dst = edge_dst[e];
  const float* arow = A + (long)src * 128;
  float4 ea = ld4(edge_attr + e * 4);
  float es = ea.x;
  float ev0 = ea.y, ev1 = ea.z, ev2 = ea.w;
  float* accrow = ACC + (long)dst * 256;

  #pragma unroll 1
  for (int u0 = 0; u0 < 32; u0 += 4) {
    float4 a0 = {0, 0, 0, 0}, a1 = {0, 0, 0, 0}, a2 = {0, 0, 0, 0}, a3 = {0, 0, 0, 0};
    #pragma unroll
    for (int j = 0; j < 64; ++j) {
      float hj = h[j];
      const float* wr = fc_w2 + j * 128 + u0;  // uniform address -> s_load
      float4 c0 = ld4(wr);
      float4 c1 = ld4(wr + 32);
      float4 c2 = ld4(wr + 64);
      float4 c3 = ld4(wr + 96);
      a0.x = fmaf(hj, c0.x, a0.x); a0.y = fmaf(hj, c0.y, a0.y);
      a0.z = fmaf(hj, c0.z, a0.z); a0.w = fmaf(hj, c0.w, a0.w);
      a1.x = fmaf(hj, c1.x, a1.x); a1.y = fmaf(hj, c1.y, a1.y);
      a1.z = fmaf(hj, c1.z, a1.z); a1.w = fmaf(hj, c1.w, a1.w);
      a2.x = fmaf(hj, c2.x, a2.x); a2.y = fmaf(hj, c2.y, a2.y);
      a2.z = fmaf(hj, c2.z, a2.z); a2.w = fmaf(hj, c2.w, a2.w);
      a3.x = fmaf(hj, c3.x, a3.x); a3.y = fmaf(hj, c3.y, a3.y);
      a3.z = fmaf(hj, c3.z, a3.z); a3.w = fmaf(hj, c3.w, a3.w);
    }

    // gather se / ve for these 4 u (aligned float4 loads)
    float4 se4 = ld4(arow + u0);
    float4 va  = ld4(arow + 32 + u0 * 3);
    float4 vb  = ld4(arow + 32 + u0 * 3 + 4);
    float4 vc  = ld4(arow + 32 + u0 * 3 + 8);

    float w0v[4] = {a0.x, a0.y, a0.z, a0.w};
    float w1v[4] = {a1.x, a1.y, a1.z, a1.w};
    float w2v[4] = {a2.x, a2.y, a2.z, a2.w};
    float w3v[4] = {a3.x, a3.y, a3.z, a3.w};
    float sev[4] = {se4.x, se4.y, se4.z, se4.w};
    float vex[4] = {va.x, va.w, vb.z, vc.y};
    float vey[4] = {va.y, vb.x, vb.w, vc.z};
    float vez[4] = {va.z, vb.y, vc.x, vc.w};

    #pragma unroll
    for (int t = 0; t < 4; ++t) {
      int u = u0 + t;
      float seu = sev[t];
      float mid_s0 = w0v[t] * seu * es;
      float dv = vex[t] * ev0 + vey[t] * ev1 + vez[t] * ev2;
      float mid_s1 = w3v[t] * dv * INV_SQRT3;
      atomicAdd(accrow + u, mid_s0);
      atomicAdd(accrow + 32 + u, mid_s1);
      float b1 = w1v[t] * seu;
      atomicAdd(accrow + 64 + u * 3 + 0, b1 * ev0);
      atomicAdd(accrow + 64 + u * 3 + 1, b1 * ev1);
      atomicAdd(accrow + 64 + u * 3 + 2, b1 * ev2);
      float b2 = w2v[t] * es;
      atomicAdd(accrow + 160 + u * 3 + 0, b2 * vex[t]);
      atomicAdd(accrow + 160 + u * 3 + 1, b2 * vey[t]);
      atomicAdd(accrow + 160 + u * 3 + 2, b2 * vez[t]);
    }
  }
}

// ---------------- Stage 2: out_s = ns @ W2s; out_v = einsum(nv, W2v); scale 0.25/8
__global__ void k3_stage2(const float* __restrict__ ACC,
                          const float* __restrict__ w2s,
                          const float* __restrict__ w2v,
                          float* __restrict__ out) {
  const float scale = 0.03125f; // (1/sqrt(16)) / sqrt(64) = 0.25/8
  int stride = gridDim.x * blockDim.x;
  for (int idx = blockIdx.x * blockDim.x + threadIdx.x; idx < NNODES * 128; idx += stride) {
    int n = idx >> 7;
    int c = idx & 127;
    const float* row = ACC + (long)n * 256;
    float acc = 0.f;
    if (c < 32) {
      #pragma unroll
      for (int q = 0; q < 64; ++q)
        acc = fmaf(row[q], w2s[q * 32 + c], acc);
    } else {
      int cc = c - 32;
      int w = cc / 3;
      int i = cc - w * 3;
      #pragma unroll
      for (int q = 0; q < 64; ++q)
        acc = fmaf(row[64 + q * 3 + i], w2v[q * 32 + w], acc);
    }
    out[idx] = acc * scale;
  }
}

extern "C" void kernel_launch(void* const* d_in, const int* in_sizes, int n_in,
                              void* d_out, int out_size, void* d_ws, size_t ws_size,
                              hipStream_t stream) {
  const float* node_input   = (const float*)d_in[0];
  // d_in[1] node_attr: unused by the reference
  const int*   edge_src     = (const int*)d_in[2];
  const int*   edge_dst     = (const int*)d_in[3];
  const float* edge_attr    = (const float*)d_in[4];
  const float* edge_scalars = (const float*)d_in[5];
  const float* w_lin1_s     = (const float*)d_in[6];
  const float* w_lin1_v     = (const float*)d_in[7];
  const float* fc_w1        = (const float*)d_in[8];
  const float* fc_w2        = (const float*)d_in[9];
  const float* w_lin2_s     = (const float*)d_in[10];
  const float* w_lin2_v     = (const float*)d_in[11];

  float* out = (float*)d_out;
  // Stage-1 output A lives in d_out (same size N*128 floats; stage2 fully
  // overwrites it afterwards). Accumulator ACC (N*256 floats) in d_ws.
  float* A   = out;
  float* ACC = (float*)d_ws;

  hipMemsetAsync(ACC, 0, (size_t)NNODES * 256 * sizeof(float), stream);

  k1_stage1<<<2048, 256, 0, stream>>>(node_input, w_lin1_s, w_lin1_v, A);
  k2_edges<<<NEDGES / 256, 256, 0, stream>>>(A, edge_src, edge_dst, edge_attr,
                                             edge_scalars, fc_w1, fc_w2, ACC);
  k3_stage2<<<2048, 256, 0, stream>>>(ACC, w_lin2_s, w_lin2_v, out);
}

// Round 2
// 1701.315 us; speedup vs baseline: 4.9729x; 4.9729x over previous
//
#include <hip/hip_runtime.h>
#include <math.h>

#define NNODES 40000
#define NEDGES 640000
#define NPB 16            // nodes per gather block
#define LROW 257          // padded LDS row stride (floats) to spread banks

__device__ __forceinline__ float4 ld4(const float* p) { return *(const float4*)p; }

__device__ __forceinline__ void lds_fadd(float* p, float v) {
#if defined(__has_builtin) && __has_builtin(__hip_atomic_fetch_add)
  __hip_atomic_fetch_add(p, v, __ATOMIC_RELAXED, __HIP_MEMORY_SCOPE_WORKGROUP);
#else
  atomicAdd(p, v);
#endif
}

// ---------------- Stage 1: s' = s @ W1s/sqrt(32); v' = einsum(v, W1v)/sqrt(32)
// A[n*128 + c]: c<32 -> s'[c]; c>=32 -> v'[w][i] at 32 + w*3 + i
__global__ void k1_stage1(const float* __restrict__ node_input,
                          const float* __restrict__ w1s,
                          const float* __restrict__ w1v,
                          float* __restrict__ A) {
  const float scale = 0.17677669529663687f; // 1/sqrt(32)
  int stride = gridDim.x * blockDim.x;
  for (int idx = blockIdx.x * blockDim.x + threadIdx.x; idx < NNODES * 128; idx += stride) {
    int n = idx >> 7;
    int c = idx & 127;
    const float* row = node_input + n * 128;
    float acc = 0.f;
    if (c < 32) {
      #pragma unroll
      for (int u = 0; u < 32; ++u)
        acc = fmaf(row[u], w1s[u * 32 + c], acc);
    } else {
      int cc = c - 32;
      int w = cc / 3;
      int i = cc - w * 3;
      #pragma unroll
      for (int u = 0; u < 32; ++u)
        acc = fmaf(row[32 + u * 3 + i], w1v[u * 32 + w], acc);
    }
    A[idx] = acc * scale;
  }
}

// ---------------- CSR build ----------------
__global__ void k_hist(const int* __restrict__ edge_dst, int* __restrict__ counts) {
  int e = blockIdx.x * blockDim.x + threadIdx.x;
  if (e < NEDGES) atomicAdd(&counts[edge_dst[e]], 1);
}

// single block, 1024 threads; exclusive scan of counts[40000] -> offsets[40001], cursor[40000]
__global__ __launch_bounds__(1024) void k_scan(const int* __restrict__ counts,
                                               int* __restrict__ offsets,
                                               int* __restrict__ cursor) {
  const int PER = 40; // 1024*40 = 40960 >= 40000
  int tid = threadIdx.x;
  int base = tid * PER;
  int s = 0;
  for (int i = 0; i < PER; ++i) {
    int idx = base + i;
    if (idx < NNODES) s += counts[idx];
  }
  __shared__ int part[1024];
  part[tid] = s;
  __syncthreads();
  for (int d = 1; d < 1024; d <<= 1) {
    int v = (tid >= d) ? part[tid - d] : 0;
    __syncthreads();
    part[tid] += v;
    __syncthreads();
  }
  int run = (tid == 0) ? 0 : part[tid - 1];
  for (int i = 0; i < PER; ++i) {
    int idx = base + i;
    if (idx < NNODES) {
      offsets[idx] = run;
      cursor[idx] = run;
      run += counts[idx];
    }
  }
  if (tid == 1023) offsets[NNODES] = part[1023];
}

__global__ void k_scatter(const int* __restrict__ edge_dst,
                          int* __restrict__ cursor, int* __restrict__ slots) {
  int e = blockIdx.x * blockDim.x + threadIdx.x;
  if (e < NEDGES) {
    int d = edge_dst[e];
    int p = atomicAdd(&cursor[d], 1);
    slots[p] = e;
  }
}

// ---------------- Gather: block = 16 nodes; edges sorted by dst; LDS accumulate
// ACC row layout (256 floats per node):
//   [0..31] s0 | [32..63] s1 | [64..159] v0 (u*3+i) | [160..255] v1 (u*3+i)
__global__ __launch_bounds__(256) void k_gather(
    const float* __restrict__ A,
    const int* __restrict__ edge_src,
    const int* __restrict__ edge_dst,
    const float* __restrict__ edge_attr,
    const float* __restrict__ edge_scalars,
    const float* __restrict__ fc_w1,
    const float* __restrict__ fc_w2,
    const int* __restrict__ offsets,
    const int* __restrict__ slots,
    float* __restrict__ ACC) {
  const float INV_SQRT8 = 0.35355339059327373f;
  const float H_SCALE   = 1.6791767923989418f / 8.0f; // SILU_NORM / sqrt(64)
  const float INV_SQRT3 = 0.57735026918962576f;

  __shared__ float lacc[NPB * LROW];
  int tid = threadIdx.x;
  for (int i = tid; i < NPB * LROW; i += 256) lacc[i] = 0.f;
  __syncthreads();

  int n0 = blockIdx.x * NPB;
  int ebase = offsets[n0];
  int eend  = offsets[n0 + NPB];

  for (int k = ebase + tid; k < eend; k += 256) {
    int e = slots[k];
    int dst = edge_dst[e];
    int ln = dst - n0;
    float* lrow = &lacc[ln * LROW];

    // edge scalars (8), pre-scaled by 1/sqrt(8)
    float4 s0 = ld4(edge_scalars + e * 8);
    float4 s1 = ld4(edge_scalars + e * 8 + 4);
    float es8[8] = {s0.x * INV_SQRT8, s0.y * INV_SQRT8, s0.z * INV_SQRT8, s0.w * INV_SQRT8,
                    s1.x * INV_SQRT8, s1.y * INV_SQRT8, s1.z * INV_SQRT8, s1.w * INV_SQRT8};

    // h[j] = silu(es8 . W1[:,j]) * SILU_NORM/8
    float h[64];
    #pragma unroll
    for (int j = 0; j < 64; ++j) {
      float x = 0.f;
      #pragma unroll
      for (int i = 0; i < 8; ++i)
        x = fmaf(es8[i], fc_w1[i * 64 + j], x);  // uniform address -> s_load
      h[j] = (x * H_SCALE) / (1.0f + __expf(-x));
    }

    int src = edge_src[e];
    const float* arow = A + (long)src * 128;
    float4 ea = ld4(edge_attr + e * 4);
    float es = ea.x;
    float ev0 = ea.y, ev1 = ea.z, ev2 = ea.w;

    #pragma unroll 1
    for (int u0 = 0; u0 < 32; u0 += 4) {
      float4 a0 = {0, 0, 0, 0}, a1 = {0, 0, 0, 0}, a2 = {0, 0, 0, 0}, a3 = {0, 0, 0, 0};
      #pragma unroll
      for (int j = 0; j < 64; ++j) {
        float hj = h[j];
        const float* wr = fc_w2 + j * 128 + u0;  // uniform address -> s_load
        float4 c0 = ld4(wr);
        float4 c1 = ld4(wr + 32);
        float4 c2 = ld4(wr + 64);
        float4 c3 = ld4(wr + 96);
        a0.x = fmaf(hj, c0.x, a0.x); a0.y = fmaf(hj, c0.y, a0.y);
        a0.z = fmaf(hj, c0.z, a0.z); a0.w = fmaf(hj, c0.w, a0.w);
        a1.x = fmaf(hj, c1.x, a1.x); a1.y = fmaf(hj, c1.y, a1.y);
        a1.z = fmaf(hj, c1.z, a1.z); a1.w = fmaf(hj, c1.w, a1.w);
        a2.x = fmaf(hj, c2.x, a2.x); a2.y = fmaf(hj, c2.y, a2.y);
        a2.z = fmaf(hj, c2.z, a2.z); a2.w = fmaf(hj, c2.w, a2.w);
        a3.x = fmaf(hj, c3.x, a3.x); a3.y = fmaf(hj, c3.y, a3.y);
        a3.z = fmaf(hj, c3.z, a3.z); a3.w = fmaf(hj, c3.w, a3.w);
      }

      float4 se4 = ld4(arow + u0);
      float4 va  = ld4(arow + 32 + u0 * 3);
      float4 vb  = ld4(arow + 32 + u0 * 3 + 4);
      float4 vc  = ld4(arow + 32 + u0 * 3 + 8);

      float w0v[4] = {a0.x, a0.y, a0.z, a0.w};
      float w1v[4] = {a1.x, a1.y, a1.z, a1.w};
      float w2v[4] = {a2.x, a2.y, a2.z, a2.w};
      float w3v[4] = {a3.x, a3.y, a3.z, a3.w};
      float sev[4] = {se4.x, se4.y, se4.z, se4.w};
      float vex[4] = {va.x, va.w, vb.z, vc.y};
      float vey[4] = {va.y, vb.x, vb.w, vc.z};
      float vez[4] = {va.z, vb.y, vc.x, vc.w};

      #pragma unroll
      for (int t = 0; t < 4; ++t) {
        int u = u0 + t;
        float seu = sev[t];
        float dv = vex[t] * ev0 + vey[t] * ev1 + vez[t] * ev2;
        lds_fadd(lrow + u,      w0v[t] * seu * es);
        lds_fadd(lrow + 32 + u, w3v[t] * dv * INV_SQRT3);
        float b1 = w1v[t] * seu;
        lds_fadd(lrow + 64 + u * 3 + 0, b1 * ev0);
        lds_fadd(lrow + 64 + u * 3 + 1, b1 * ev1);
        lds_fadd(lrow + 64 + u * 3 + 2, b1 * ev2);
        float b2 = w2v[t] * es;
        lds_fadd(lrow + 160 + u * 3 + 0, b2 * vex[t]);
        lds_fadd(lrow + 160 + u * 3 + 1, b2 * vey[t]);
        lds_fadd(lrow + 160 + u * 3 + 2, b2 * vez[t]);
      }
    }
  }
  __syncthreads();

  // write 16 node rows (coalesced)
  for (int i = tid; i < NPB * 256; i += 256) {
    int nl = i >> 8;
    int c  = i & 255;
    ACC[(long)(n0 + nl) * 256 + c] = lacc[nl * LROW + c];
  }
}

// ---------------- Stage 2: out_s = ns @ W2s; out_v = einsum(nv, W2v); scale 0.25/8
__global__ void k3_stage2(const float* __restrict__ ACC,
                          const float* __restrict__ w2s,
                          const float* __restrict__ w2v,
                          float* __restrict__ out) {
  const float scale = 0.03125f; // (1/sqrt(16)) / sqrt(64)
  int stride = gridDim.x * blockDim.x;
  for (int idx = blockIdx.x * blockDim.x + threadIdx.x; idx < NNODES * 128; idx += stride) {
    int n = idx >> 7;
    int c = idx & 127;
    const float* row = ACC + (long)n * 256;
    float acc = 0.f;
    if (c < 32) {
      #pragma unroll
      for (int q = 0; q < 64; ++q)
        acc = fmaf(row[q], w2s[q * 32 + c], acc);
    } else {
      int cc = c - 32;
      int w = cc / 3;
      int i = cc - w * 3;
      #pragma unroll
      for (int q = 0; q < 64; ++q)
        acc = fmaf(row[64 + q * 3 + i], w2v[q * 32 + w], acc);
    }
    out[idx] = acc * scale;
  }
}

extern "C" void kernel_launch(void* const* d_in, const int* in_sizes, int n_in,
                              void* d_out, int out_size, void* d_ws, size_t ws_size,
                              hipStream_t stream) {
  const float* node_input   = (const float*)d_in[0];
  const int*   edge_src     = (const int*)d_in[2];
  const int*   edge_dst     = (const int*)d_in[3];
  const float* edge_attr    = (const float*)d_in[4];
  const float* edge_scalars = (const float*)d_in[5];
  const float* w_lin1_s     = (const float*)d_in[6];
  const float* w_lin1_v     = (const float*)d_in[7];
  const float* fc_w1        = (const float*)d_in[8];
  const float* fc_w2        = (const float*)d_in[9];
  const float* w_lin2_s     = (const float*)d_in[10];
  const float* w_lin2_v     = (const float*)d_in[11];

  float* out = (float*)d_out;
  float* A   = out;  // stage-1 output lives in d_out; stage2 overwrites later

  // ws layout
  char* p = (char*)d_ws;
  float* ACC     = (float*)p;                 p += (size_t)NNODES * 256 * sizeof(float);
  int*   counts  = (int*)p;                   p += (size_t)NNODES * sizeof(int);
  int*   offsets = (int*)p;                   p += (size_t)(NNODES + 1) * sizeof(int);
  int*   cursor  = (int*)p;                   p += (size_t)NNODES * sizeof(int);
  int*   slots   = (int*)p;                   p += (size_t)NEDGES * sizeof(int);

  hipMemsetAsync(counts, 0, (size_t)NNODES * sizeof(int), stream);

  k1_stage1<<<2048, 256, 0, stream>>>(node_input, w_lin1_s, w_lin1_v, A);
  k_hist<<<(NEDGES + 255) / 256, 256, 0, stream>>>(edge_dst, counts);
  k_scan<<<1, 1024, 0, stream>>>(counts, offsets, cursor);
  k_scatter<<<(NEDGES + 255) / 256, 256, 0, stream>>>(edge_dst, cursor, slots);
  k_gather<<<NNODES / NPB, 256, 0, stream>>>(A, edge_src, edge_dst, edge_attr,
                                             edge_scalars, fc_w1, fc_w2,
                                             offsets, slots, ACC);
  k3_stage2<<<2048, 256, 0, stream>>>(ACC, w_lin2_s, w_lin2_v, out);
}

// Round 3
// 1270.981 us; speedup vs baseline: 6.6566x; 1.3386x over previous
//
#include <hip/hip_runtime.h>
#include <math.h>

#define NNODES 40000
#define NEDGES 640000
#define NPB 16            // nodes per edge-block
#define LROW 257          // padded LDS accumulator row stride (floats)

typedef __attribute__((ext_vector_type(8))) short short8_t;
typedef __attribute__((ext_vector_type(4))) float float4_t;

__device__ __forceinline__ float4 ld4(const float* p) { return *(const float4*)p; }

__device__ __forceinline__ unsigned short bf16r(float x) {
  union { float f; unsigned u; } v; v.f = x;
  unsigned u = v.u;
  u += 0x7FFFu + ((u >> 16) & 1u);   // RNE
  return (unsigned short)(u >> 16);
}

__device__ __forceinline__ void lds_fadd(float* p, float v) {
  __hip_atomic_fetch_add(p, v, __ATOMIC_RELAXED, __HIP_MEMORY_SCOPE_WORKGROUP);
}

// ---------------- Stage 1: s' = s @ W1s/sqrt(32); v' = einsum(v, W1v)/sqrt(32)
// A[n*128 + c]: c<32 -> s'[c]; c>=32 -> v'[w][i] at 32 + w*3 + i
__global__ void k1_stage1(const float* __restrict__ node_input,
                          const float* __restrict__ w1s,
                          const float* __restrict__ w1v,
                          float* __restrict__ A) {
  const float scale = 0.17677669529663687f; // 1/sqrt(32)
  int stride = gridDim.x * blockDim.x;
  for (int idx = blockIdx.x * blockDim.x + threadIdx.x; idx < NNODES * 128; idx += stride) {
    int n = idx >> 7;
    int c = idx & 127;
    const float* row = node_input + n * 128;
    float acc = 0.f;
    if (c < 32) {
      #pragma unroll
      for (int u = 0; u < 32; ++u)
        acc = fmaf(row[u], w1s[u * 32 + c], acc);
    } else {
      int cc = c - 32;
      int w = cc / 3;
      int i = cc - w * 3;
      #pragma unroll
      for (int u = 0; u < 32; ++u)
        acc = fmaf(row[32 + u * 3 + i], w1v[u * 32 + w], acc);
    }
    A[idx] = acc * scale;
  }
}

// ---------------- CSR build ----------------
__global__ void k_hist(const int* __restrict__ edge_dst, int* __restrict__ counts) {
  int e = blockIdx.x * blockDim.x + threadIdx.x;
  if (e < NEDGES) atomicAdd(&counts[edge_dst[e]], 1);
}

// two-level scan: A) per-block sums, B) scan of 157 block sums, C) per-block scan + add
__global__ void k_scanA(const int* __restrict__ counts, int* __restrict__ bsum) {
  __shared__ int ws[4];
  int t = blockIdx.x * 256 + threadIdx.x;
  int v = (t < NNODES) ? counts[t] : 0;
  for (int d = 32; d; d >>= 1) v += __shfl_down(v, d, 64);
  if ((threadIdx.x & 63) == 0) ws[threadIdx.x >> 6] = v;
  __syncthreads();
  if (threadIdx.x == 0) bsum[blockIdx.x] = ws[0] + ws[1] + ws[2] + ws[3];
}

__global__ __launch_bounds__(256) void k_scanB(const int* __restrict__ bsum,
                                               int* __restrict__ boff,
                                               int* __restrict__ offsets) {
  __shared__ int s[256];
  int tid = threadIdx.x;
  int v = (tid < 157) ? bsum[tid] : 0;
  s[tid] = v;
  __syncthreads();
  for (int d = 1; d < 256; d <<= 1) {
    int x = (tid >= d) ? s[tid - d] : 0;
    __syncthreads();
    s[tid] += x;
    __syncthreads();
  }
  if (tid < 157) boff[tid] = s[tid] - v;
  if (tid == 0) offsets[NNODES] = NEDGES;
}

__global__ __launch_bounds__(256) void k_scanC(const int* __restrict__ counts,
                                               const int* __restrict__ boff,
                                               int* __restrict__ offsets,
                                               int* __restrict__ cursor) {
  __shared__ int s[256];
  int tid = threadIdx.x;
  int t = blockIdx.x * 256 + tid;
  int v = (t < NNODES) ? counts[t] : 0;
  s[tid] = v;
  __syncthreads();
  for (int d = 1; d < 256; d <<= 1) {
    int x = (tid >= d) ? s[tid - d] : 0;
    __syncthreads();
    s[tid] += x;
    __syncthreads();
  }
  int off = boff[blockIdx.x] + s[tid] - v;
  if (t < NNODES) { offsets[t] = off; cursor[t] = off; }
}

__global__ void k_scatter(const int* __restrict__ edge_dst,
                          int* __restrict__ cursor, int* __restrict__ slots) {
  int e = blockIdx.x * blockDim.x + threadIdx.x;
  if (e < NEDGES) {
    int d = edge_dst[e];
    int p = atomicAdd(&cursor[d], 1);
    slots[p] = e;
  }
}

// ---------------- Fused edge kernel: MLP via MFMA + tensor product + LDS reduce
// Block = 16 nodes; loops over 64-edge chunks of its sorted edge range.
// ACC row (256 floats/node): [0..31] s0 | [32..63] s1 | [64..159] v0 | [160..255] v1
__global__ __launch_bounds__(256, 2) void k_edge(
    const float* __restrict__ A,
    const int* __restrict__ edge_src,
    const int* __restrict__ edge_dst,
    const float* __restrict__ edge_attr,
    const float* __restrict__ edge_scalars,
    const float* __restrict__ fc_w1,
    const float* __restrict__ fc_w2,
    const int* __restrict__ offsets,
    const int* __restrict__ slots,
    float* __restrict__ ACC) {
  const float INV_SQRT8 = 0.35355339059327373f;
  const float H_SCALE   = 1.6791767923989418f / 8.0f; // SILU_NORM / sqrt(64)
  const float INV_SQRT3 = 0.57735026918962576f;

  __shared__ float    lacc[NPB * LROW];
  __shared__ short8_t h_frag[8 * 64];   // [(wtile*2+kh)*64 + lane]: A-frag-ready h
  __shared__ short8_t w2frag[16 * 64];  // [(ctile*2+kh)*64 + lane]: B-frag-ready w2
  __shared__ float    w1t[64 * 8];      // fc_w1 transposed, pre-scaled
  __shared__ int      src_lds[64];
  __shared__ int      ln_lds[64];
  __shared__ float4   ea_lds[64];

  int tid = threadIdx.x;
  int n0 = blockIdx.x * NPB;
  int ebase = offsets[n0];
  int eend  = offsets[n0 + NPB];

  for (int i = tid; i < NPB * LROW; i += 256) lacc[i] = 0.f;
  for (int i = tid; i < 512; i += 256) {
    int j = i >> 3, ii = i & 7;
    w1t[i] = fc_w1[ii * 64 + j] * INV_SQRT8;
  }
  // stage w2 (fp32 global) into bf16 B-fragment layout:
  // frag f=(ctile*2+kh), lane l: elem j = w2[k = kh*32 + (l>>4)*8 + j][c = ctile*16 + (l&15)]
  for (int fi = tid; fi < 16 * 64; fi += 256) {
    int f = fi >> 6, l = fi & 63;
    int ct = f >> 1, kh = f & 1, mm = l & 15, qq = l >> 4;
    short8_t v;
    #pragma unroll
    for (int j = 0; j < 8; ++j)
      v[j] = (short)bf16r(fc_w2[(kh * 32 + qq * 8 + j) * 128 + ct * 16 + mm]);
    w2frag[fi] = v;
  }
  __syncthreads();

  int wv = tid >> 6;       // wave id 0..3
  int l  = tid & 63;
  int m  = l & 15;
  int q  = l >> 4;

  for (int k0 = ebase; k0 < eend; k0 += 64) {
    // ---- phase 1: compute h (bf16) for 64 edges; wave 0 stages edge metadata
    {
      int kk = k0 + l;                       // this thread's chunk-edge = lane
      bool valid = kk < eend;
      int e = slots[valid ? kk : (eend - 1)];
      if (wv == 0) {
        src_lds[l] = edge_src[e];
        ln_lds[l]  = edge_dst[e] - n0;
        ea_lds[l]  = ld4(edge_attr + (long)e * 4);
      }
      float4 sA = ld4(edge_scalars + (long)e * 8);
      float4 sB = ld4(edge_scalars + (long)e * 8 + 4);
      float es8[8] = {sA.x, sA.y, sA.z, sA.w, sB.x, sB.y, sB.z, sB.w};
      unsigned short hh[16];
      #pragma unroll
      for (int jj = 0; jj < 16; ++jj) {
        int j = wv * 16 + jj;
        float4 wA = *(const float4*)&w1t[j * 8];
        float4 wB = *(const float4*)&w1t[j * 8 + 4];
        float x = es8[0]*wA.x + es8[1]*wA.y + es8[2]*wA.z + es8[3]*wA.w
                + es8[4]*wB.x + es8[5]*wB.y + es8[6]*wB.z + es8[7]*wB.w;
        float hv = valid ? (x * H_SCALE) / (1.f + __expf(-x)) : 0.f;
        hh[jj] = bf16r(hv);
      }
      // store in A-frag layout: edge tile w = l>>4? no: edge = l -> tile l>>4, row l&15
      int wrow = l >> 4;           // which 16-edge tile this edge belongs to
      int mm   = l & 15;
      int kh   = wv >> 1;          // j range [wv*16, wv*16+16) -> k-half
      int qp   = (wv & 1) * 2;     // first of two k-quads covered
      short8_t v0, v1;
      #pragma unroll
      for (int j = 0; j < 8; ++j) { v0[j] = (short)hh[j]; v1[j] = (short)hh[8 + j]; }
      h_frag[(wrow * 2 + kh) * 64 + qp * 16 + mm]       = v0;
      h_frag[(wrow * 2 + kh) * 64 + (qp + 1) * 16 + mm] = v1;
    }
    __syncthreads();

    // ---- phase 2: MFMA (w = h @ w2) + tensor-product epilogue + LDS reduce
    {
      short8_t a0 = h_frag[(wv * 2 + 0) * 64 + l];
      short8_t a1 = h_frag[(wv * 2 + 1) * 64 + l];
      float4_t acc[8];
      #pragma unroll
      for (int t = 0; t < 8; ++t) {
        acc[t] = (float4_t){0.f, 0.f, 0.f, 0.f};
        short8_t b0 = w2frag[(t * 2 + 0) * 64 + l];
        short8_t b1 = w2frag[(t * 2 + 1) * 64 + l];
        acc[t] = __builtin_amdgcn_mfma_f32_16x16x32_bf16(a0, b0, acc[t], 0, 0, 0);
        acc[t] = __builtin_amdgcn_mfma_f32_16x16x32_bf16(a1, b1, acc[t], 0, 0, 0);
      }
      // C layout: channel = tile*16 + (l&15), edge-row = q*4 + reg
      #pragma unroll
      for (int r = 0; r < 4; ++r) {
        int ec = wv * 16 + q * 4 + r;       // chunk-edge this reg belongs to
        if (k0 + ec < eend) {
          int ln  = ln_lds[ec];
          int src = src_lds[ec];
          float4 ea = ea_lds[ec];
          const float* ab = A + (long)src * 128;
          float* lrow = lacc + ln * LROW;
          float esc = ea.x, ev0 = ea.y, ev1 = ea.z, ev2 = ea.w;
          #pragma unroll
          for (int uo = 0; uo < 2; ++uo) {
            int u = m + uo * 16;
            float w0 = acc[0 + uo][r];
            float w1 = acc[2 + uo][r];
            float w2 = acc[4 + uo][r];
            float w3 = acc[6 + uo][r];
            float se = ab[u];
            float vx = ab[32 + u * 3], vy = ab[33 + u * 3], vz = ab[34 + u * 3];
            lds_fadd(lrow + u, w0 * se * esc);
            float dv = vx * ev0 + vy * ev1 + vz * ev2;
            lds_fadd(lrow + 32 + u, w3 * dv * INV_SQRT3);
            float b1v = w1 * se;
            lds_fadd(lrow + 64 + u * 3 + 0, b1v * ev0);
            lds_fadd(lrow + 64 + u * 3 + 1, b1v * ev1);
            lds_fadd(lrow + 64 + u * 3 + 2, b1v * ev2);
            float b2v = w2 * esc;
            lds_fadd(lrow + 160 + u * 3 + 0, b2v * vx);
            lds_fadd(lrow + 160 + u * 3 + 1, b2v * vy);
            lds_fadd(lrow + 160 + u * 3 + 2, b2v * vz);
          }
        }
      }
    }
    __syncthreads();
  }

  // write 16 node rows (coalesced); fully covers ACC (no memset needed)
  for (int i = tid; i < NPB * 256; i += 256) {
    int node = i >> 8;
    int c = i & 255;
    ACC[(long)(n0 + node) * 256 + c] = lacc[node * LROW + c];
  }
}

// ---------------- Stage 2: out_s = ns @ W2s; out_v = einsum(nv, W2v); scale 0.25/8
__global__ void k3_stage2(const float* __restrict__ ACC,
                          const float* __restrict__ w2s,
                          const float* __restrict__ w2v,
                          float* __restrict__ out) {
  const float scale = 0.03125f; // (1/sqrt(16)) / sqrt(64)
  int stride = gridDim.x * blockDim.x;
  for (int idx = blockIdx.x * blockDim.x + threadIdx.x; idx < NNODES * 128; idx += stride) {
    int n = idx >> 7;
    int c = idx & 127;
    const float* row = ACC + (long)n * 256;
    float acc = 0.f;
    if (c < 32) {
      #pragma unroll
      for (int q = 0; q < 64; ++q)
        acc = fmaf(row[q], w2s[q * 32 + c], acc);
    } else {
      int cc = c - 32;
      int w = cc / 3;
      int i = cc - w * 3;
      #pragma unroll
      for (int q = 0; q < 64; ++q)
        acc = fmaf(row[64 + q * 3 + i], w2v[q * 32 + w], acc);
    }
    out[idx] = acc * scale;
  }
}

extern "C" void kernel_launch(void* const* d_in, const int* in_sizes, int n_in,
                              void* d_out, int out_size, void* d_ws, size_t ws_size,
                              hipStream_t stream) {
  const float* node_input   = (const float*)d_in[0];
  const int*   edge_src     = (const int*)d_in[2];
  const int*   edge_dst     = (const int*)d_in[3];
  const float* edge_attr    = (const float*)d_in[4];
  const float* edge_scalars = (const float*)d_in[5];
  const float* w_lin1_s     = (const float*)d_in[6];
  const float* w_lin1_v     = (const float*)d_in[7];
  const float* fc_w1        = (const float*)d_in[8];
  const float* fc_w2        = (const float*)d_in[9];
  const float* w_lin2_s     = (const float*)d_in[10];
  const float* w_lin2_v     = (const float*)d_in[11];

  float* out = (float*)d_out;
  float* Abuf = out;  // stage-1 output lives in d_out; k3 overwrites it after k_edge

  // ws layout (16B-aligned bumps)
  char* p = (char*)d_ws;
  float* ACC     = (float*)p;  p += (size_t)NNODES * 256 * sizeof(float);
  int*   counts  = (int*)p;    p += (size_t)NNODES * sizeof(int);
  int*   offsets = (int*)p;    p += (size_t)(NNODES + 4) * sizeof(int);
  int*   cursor  = (int*)p;    p += (size_t)NNODES * sizeof(int);
  int*   slots   = (int*)p;    p += (size_t)NEDGES * sizeof(int);
  int*   bsum    = (int*)p;    p += 160 * sizeof(int);
  int*   boff    = (int*)p;    p += 160 * sizeof(int);

  hipMemsetAsync(counts, 0, (size_t)NNODES * sizeof(int), stream);

  k1_stage1<<<2048, 256, 0, stream>>>(node_input, w_lin1_s, w_lin1_v, Abuf);
  k_hist<<<NEDGES / 256, 256, 0, stream>>>(edge_dst, counts);
  k_scanA<<<157, 256, 0, stream>>>(counts, bsum);
  k_scanB<<<1, 256, 0, stream>>>(bsum, boff, offsets);
  k_scanC<<<157, 256, 0, stream>>>(counts, boff, offsets, cursor);
  k_scatter<<<NEDGES / 256, 256, 0, stream>>>(edge_dst, cursor, slots);
  k_edge<<<NNODES / NPB, 256, 0, stream>>>(Abuf, edge_src, edge_dst, edge_attr,
                                           edge_scalars, fc_w1, fc_w2,
                                           offsets, slots, ACC);
  k3_stage2<<<2048, 256, 0, stream>>>(ACC, w_lin2_s, w_lin2_v, out);
}

// Round 7
// 1258.922 us; speedup vs baseline: 6.7203x; 1.0096x over previous
//
#include <hip/hip_runtime.h>
#include <math.h>

#define NNODES 40000
#define NEDGES 640000
#define NPB 8             // nodes per edge-block (16->8: LDS 45->28 KB, 4 blk/CU)
#define LROW 257          // padded LDS accumulator row stride (floats)

typedef __attribute__((ext_vector_type(8))) short short8_t;
typedef __attribute__((ext_vector_type(4))) float float4_t;

__device__ __forceinline__ float4 ld4(const float* p) { return *(const float4*)p; }

__device__ __forceinline__ unsigned short bf16r(float x) {
  union { float f; unsigned u; } v; v.f = x;
  unsigned u = v.u;
  u += 0x7FFFu + ((u >> 16) & 1u);   // RNE
  return (unsigned short)(u >> 16);
}

__device__ __forceinline__ void lds_fadd(float* p, float v) {
  __hip_atomic_fetch_add(p, v, __ATOMIC_RELAXED, __HIP_MEMORY_SCOPE_WORKGROUP);
}

// ---------------- Stage 1: s' = s @ W1s/sqrt(32); v' = einsum(v, W1v)/sqrt(32)
// A[n*128 + c]: c<32 -> s'[c]; c>=32 -> v'[w][i] at 32 + w*3 + i
__global__ void k1_stage1(const float* __restrict__ node_input,
                          const float* __restrict__ w1s,
                          const float* __restrict__ w1v,
                          float* __restrict__ A) {
  const float scale = 0.17677669529663687f; // 1/sqrt(32)
  int stride = gridDim.x * blockDim.x;
  for (int idx = blockIdx.x * blockDim.x + threadIdx.x; idx < NNODES * 128; idx += stride) {
    int n = idx >> 7;
    int c = idx & 127;
    const float* row = node_input + n * 128;
    float acc = 0.f;
    if (c < 32) {
      #pragma unroll
      for (int u = 0; u < 32; ++u)
        acc = fmaf(row[u], w1s[u * 32 + c], acc);
    } else {
      int cc = c - 32;
      int w = cc / 3;
      int i = cc - w * 3;
      #pragma unroll
      for (int u = 0; u < 32; ++u)
        acc = fmaf(row[32 + u * 3 + i], w1v[u * 32 + w], acc);
    }
    A[idx] = acc * scale;
  }
}

// ---------------- CSR build (round-3 proven, byte-identical) ----------------
__global__ void k_hist(const int* __restrict__ edge_dst, int* __restrict__ counts) {
  int e = blockIdx.x * blockDim.x + threadIdx.x;
  if (e < NEDGES) atomicAdd(&counts[edge_dst[e]], 1);
}

__global__ void k_scanA(const int* __restrict__ counts, int* __restrict__ bsum) {
  __shared__ int ws[4];
  int t = blockIdx.x * 256 + threadIdx.x;
  int v = (t < NNODES) ? counts[t] : 0;
  for (int d = 32; d; d >>= 1) v += __shfl_down(v, d, 64);
  if ((threadIdx.x & 63) == 0) ws[threadIdx.x >> 6] = v;
  __syncthreads();
  if (threadIdx.x == 0) bsum[blockIdx.x] = ws[0] + ws[1] + ws[2] + ws[3];
}

__global__ __launch_bounds__(256) void k_scanB(const int* __restrict__ bsum,
                                               int* __restrict__ boff,
                                               int* __restrict__ offsets) {
  __shared__ int s[256];
  int tid = threadIdx.x;
  int v = (tid < 157) ? bsum[tid] : 0;
  s[tid] = v;
  __syncthreads();
  for (int d = 1; d < 256; d <<= 1) {
    int x = (tid >= d) ? s[tid - d] : 0;
    __syncthreads();
    s[tid] += x;
    __syncthreads();
  }
  if (tid < 157) boff[tid] = s[tid] - v;
  if (tid == 0) offsets[NNODES] = NEDGES;
}

__global__ __launch_bounds__(256) void k_scanC(const int* __restrict__ counts,
                                               const int* __restrict__ boff,
                                               int* __restrict__ offsets,
                                               int* __restrict__ cursor) {
  __shared__ int s[256];
  int tid = threadIdx.x;
  int t = blockIdx.x * 256 + tid;
  int v = (t < NNODES) ? counts[t] : 0;
  s[tid] = v;
  __syncthreads();
  for (int d = 1; d < 256; d <<= 1) {
    int x = (tid >= d) ? s[tid - d] : 0;
    __syncthreads();
    s[tid] += x;
    __syncthreads();
  }
  int off = boff[blockIdx.x] + s[tid] - v;
  if (t < NNODES) { offsets[t] = off; cursor[t] = off; }
}

__global__ void k_scatter(const int* __restrict__ edge_dst,
                          int* __restrict__ cursor, int* __restrict__ slots) {
  int e = blockIdx.x * blockDim.x + threadIdx.x;
  if (e < NEDGES) {
    int d = edge_dst[e];
    int p = atomicAdd(&cursor[d], 1);
    slots[p] = e;
  }
}

// ---------------- Fused edge kernel (R3 structure, two deltas):
// (1) interleaved edge->tile map: MFMA tile w holds chunk-edges {w + 4*row},
//     so output reg (q,r) of wave wv maps to chunk-edge wv + 16q + 4r. The 4
//     q-lane-groups of one lds_fadd instruction then hit edges 16 slots apart
//     (different dst rows) -> same-address atomic serialization eliminated.
//     (R3 mapped (q,r)->wv*16+q*4+r: 4 q-groups on consecutive same-dst edges
//     -> 4-way same-address serialization on every atomic.)
// (2) NPB 16->8, __launch_bounds__(256,4): 28 KB LDS -> 4 blocks/CU (was 2.4).
// ACC row (256 floats/node): [0..31] s0 | [32..63] s1 | [64..159] v0 | [160..255] v1
__global__ __launch_bounds__(256, 4) void k_edge(
    const float* __restrict__ A,
    const int* __restrict__ edge_src,
    const int* __restrict__ edge_dst,
    const float* __restrict__ edge_attr,
    const float* __restrict__ edge_scalars,
    const float* __restrict__ fc_w1,
    const float* __restrict__ fc_w2,
    const int* __restrict__ offsets,
    const int* __restrict__ slots,
    float* __restrict__ ACC) {
  const float INV_SQRT8 = 0.35355339059327373f;
  const float H_SCALE   = 1.6791767923989418f / 8.0f; // SILU_NORM / sqrt(64)
  const float INV_SQRT3 = 0.57735026918962576f;

  __shared__ float    lacc[NPB * LROW];
  __shared__ short8_t h_frag[8 * 64];   // [(tile*2+kh)*64 + lane]: A-frag-ready h
  __shared__ short8_t w2frag[16 * 64];  // [(ctile*2+kh)*64 + lane]: B-frag-ready w2
  __shared__ float    w1t[64 * 8];      // fc_w1 transposed, pre-scaled
  __shared__ int      src_lds[64];
  __shared__ int      ln_lds[64];
  __shared__ float4   ea_lds[64];

  int tid = threadIdx.x;
  int n0 = blockIdx.x * NPB;
  int ebase = offsets[n0];
  int eend  = offsets[n0 + NPB];

  for (int i = tid; i < NPB * LROW; i += 256) lacc[i] = 0.f;
  for (int i = tid; i < 512; i += 256) {
    int j = i >> 3, ii = i & 7;
    w1t[i] = fc_w1[ii * 64 + j] * INV_SQRT8;
  }
  // B-frag layout (R3-proven): frag f=(ct*2+kh), lane l holds
  // elem j = w2[k = kh*32 + (l>>4)*8 + j][c = ct*16 + (l&15)]
  for (int fi = tid; fi < 16 * 64; fi += 256) {
    int f = fi >> 6, ll = fi & 63;
    int ct = f >> 1, kh = f & 1, mm = ll & 15, qq = ll >> 4;
    short8_t v;
    #pragma unroll
    for (int j = 0; j < 8; ++j)
      v[j] = (short)bf16r(fc_w2[(kh * 32 + qq * 8 + j) * 128 + ct * 16 + mm]);
    w2frag[fi] = v;
  }
  __syncthreads();

  int wv = tid >> 6;       // wave id 0..3
  int l  = tid & 63;
  int m  = l & 15;
  int q  = l >> 4;

  for (int k0 = ebase; k0 < eend; k0 += 64) {
    // ---- phase 1: compute h (bf16) for 64 edges; wave 0 stages edge metadata
    {
      int kk = k0 + l;                       // this thread's chunk-edge = lane
      bool valid = kk < eend;
      int e = slots[valid ? kk : (eend - 1)];
      if (wv == 0) {
        src_lds[l] = edge_src[e];
        ln_lds[l]  = edge_dst[e] - n0;
        ea_lds[l]  = ld4(edge_attr + (long)e * 4);
      }
      float4 sA = ld4(edge_scalars + (long)e * 8);
      float4 sB = ld4(edge_scalars + (long)e * 8 + 4);
      float es8[8] = {sA.x, sA.y, sA.z, sA.w, sB.x, sB.y, sB.z, sB.w};
      unsigned short hh[16];
      #pragma unroll
      for (int jj = 0; jj < 16; ++jj) {
        int j = wv * 16 + jj;
        float4 wA = *(const float4*)&w1t[j * 8];
        float4 wB = *(const float4*)&w1t[j * 8 + 4];
        float x = es8[0]*wA.x + es8[1]*wA.y + es8[2]*wA.z + es8[3]*wA.w
                + es8[4]*wB.x + es8[5]*wB.y + es8[6]*wB.z + es8[7]*wB.w;
        float hv = valid ? (x * H_SCALE) / (1.f + __expf(-x)) : 0.f;
        hh[jj] = bf16r(hv);
      }
      // interleaved tile map: chunk-edge l -> tile (l&3), A-frag row (l>>2)
      int wrow = l & 3;
      int mm   = l >> 2;
      int kh   = wv >> 1;          // j range [wv*16, wv*16+16) -> k-half
      int qp   = (wv & 1) * 2;     // first of two k-quads covered
      short8_t v0, v1;
      #pragma unroll
      for (int j = 0; j < 8; ++j) { v0[j] = (short)hh[j]; v1[j] = (short)hh[8 + j]; }
      h_frag[(wrow * 2 + kh) * 64 + qp * 16 + mm]       = v0;
      h_frag[(wrow * 2 + kh) * 64 + (qp + 1) * 16 + mm] = v1;
    }
    __syncthreads();

    // ---- phase 2: MFMA (w = h @ w2) + tensor-product epilogue + LDS reduce
    {
      short8_t a0 = h_frag[(wv * 2 + 0) * 64 + l];
      short8_t a1 = h_frag[(wv * 2 + 1) * 64 + l];
      float4_t acc[8];
      #pragma unroll
      for (int t = 0; t < 8; ++t) {
        acc[t] = (float4_t){0.f, 0.f, 0.f, 0.f};
        short8_t b0 = w2frag[(t * 2 + 0) * 64 + l];
        short8_t b1 = w2frag[(t * 2 + 1) * 64 + l];
        acc[t] = __builtin_amdgcn_mfma_f32_16x16x32_bf16(a0, b0, acc[t], 0, 0, 0);
        acc[t] = __builtin_amdgcn_mfma_f32_16x16x32_bf16(a1, b1, acc[t], 0, 0, 0);
      }
      // C reg (q,r) of wave wv -> tile row q*4+r -> chunk-edge wv + 16q + 4r
      #pragma unroll
      for (int r = 0; r < 4; ++r) {
        int ec = wv + 16 * q + 4 * r;
        if (k0 + ec < eend) {
          int ln  = ln_lds[ec];
          int src = src_lds[ec];
          float4 ea = ea_lds[ec];
          const float* ab = A + (long)src * 128;
          float* lrow = lacc + ln * LROW;
          float esc = ea.x, ev0 = ea.y, ev1 = ea.z, ev2 = ea.w;
          #pragma unroll
          for (int uo = 0; uo < 2; ++uo) {
            int u = m + uo * 16;
            float w0 = acc[0 + uo][r];
            float w1 = acc[2 + uo][r];
            float w2 = acc[4 + uo][r];
            float w3 = acc[6 + uo][r];
            float se = ab[u];
            float vx = ab[32 + u * 3], vy = ab[33 + u * 3], vz = ab[34 + u * 3];
            lds_fadd(lrow + u, w0 * se * esc);
            float dv = vx * ev0 + vy * ev1 + vz * ev2;
            lds_fadd(lrow + 32 + u, w3 * dv * INV_SQRT3);
            float b1v = w1 * se;
            lds_fadd(lrow + 64 + u * 3 + 0, b1v * ev0);
            lds_fadd(lrow + 64 + u * 3 + 1, b1v * ev1);
            lds_fadd(lrow + 64 + u * 3 + 2, b1v * ev2);
            float b2v = w2 * esc;
            lds_fadd(lrow + 160 + u * 3 + 0, b2v * vx);
            lds_fadd(lrow + 160 + u * 3 + 1, b2v * vy);
            lds_fadd(lrow + 160 + u * 3 + 2, b2v * vz);
          }
        }
      }
    }
    __syncthreads();
  }

  // write NPB node rows (coalesced); fully covers ACC (no memset needed)
  for (int i = tid; i < NPB * 256; i += 256) {
    int node = i >> 8;
    int c = i & 255;
    ACC[(long)(n0 + node) * 256 + c] = lacc[node * LROW + c];
  }
}

// ---------------- Stage 2: out_s = ns @ W2s; out_v = einsum(nv, W2v); scale 0.25/8
__global__ void k3_stage2(const float* __restrict__ ACC,
                          const float* __restrict__ w2s,
                          const float* __restrict__ w2v,
                          float* __restrict__ out) {
  const float scale = 0.03125f; // (1/sqrt(16)) / sqrt(64)
  int stride = gridDim.x * blockDim.x;
  for (int idx = blockIdx.x * blockDim.x + threadIdx.x; idx < NNODES * 128; idx += stride) {
    int n = idx >> 7;
    int c = idx & 127;
    const float* row = ACC + (long)n * 256;
    float acc = 0.f;
    if (c < 32) {
      #pragma unroll
      for (int qq = 0; qq < 64; ++qq)
        acc = fmaf(row[qq], w2s[qq * 32 + c], acc);
    } else {
      int cc = c - 32;
      int w = cc / 3;
      int i = cc - w * 3;
      #pragma unroll
      for (int qq = 0; qq < 64; ++qq)
        acc = fmaf(row[64 + qq * 3 + i], w2v[qq * 32 + w], acc);
    }
    out[idx] = acc * scale;
  }
}

extern "C" void kernel_launch(void* const* d_in, const int* in_sizes, int n_in,
                              void* d_out, int out_size, void* d_ws, size_t ws_size,
                              hipStream_t stream) {
  const float* node_input   = (const float*)d_in[0];
  const int*   edge_src     = (const int*)d_in[2];
  const int*   edge_dst     = (const int*)d_in[3];
  const float* edge_attr    = (const float*)d_in[4];
  const float* edge_scalars = (const float*)d_in[5];
  const float* w_lin1_s     = (const float*)d_in[6];
  const float* w_lin1_v     = (const float*)d_in[7];
  const float* fc_w1        = (const float*)d_in[8];
  const float* fc_w2        = (const float*)d_in[9];
  const float* w_lin2_s     = (const float*)d_in[10];
  const float* w_lin2_v     = (const float*)d_in[11];

  float* out = (float*)d_out;
  float* Abuf = out;  // stage-1 output lives in d_out; k3 overwrites it after k_edge

  // ws layout — identical footprint to the round-3 build (proven to fit)
  char* p = (char*)d_ws;
  float* ACC    = (float*)p;  p += (size_t)NNODES * 256 * sizeof(float);
  int* counts   = (int*)p;    p += (size_t)NNODES * sizeof(int);
  int* offsets  = (int*)p;    p += (size_t)(NNODES + 4) * sizeof(int);
  int* cursor   = (int*)p;    p += (size_t)NNODES * sizeof(int);
  int* slots    = (int*)p;    p += (size_t)NEDGES * sizeof(int);
  int* bsum     = (int*)p;    p += 160 * sizeof(int);
  int* boff     = (int*)p;    p += 160 * sizeof(int);

  hipMemsetAsync(counts, 0, (size_t)NNODES * sizeof(int), stream);

  k1_stage1<<<2048, 256, 0, stream>>>(node_input, w_lin1_s, w_lin1_v, Abuf);
  k_hist<<<NEDGES / 256, 256, 0, stream>>>(edge_dst, counts);
  k_scanA<<<157, 256, 0, stream>>>(counts, bsum);
  k_scanB<<<1, 256, 0, stream>>>(bsum, boff, offsets);
  k_scanC<<<157, 256, 0, stream>>>(counts, boff, offsets, cursor);
  k_scatter<<<NEDGES / 256, 256, 0, stream>>>(edge_dst, cursor, slots);
  k_edge<<<NNODES / NPB, 256, 0, stream>>>(Abuf, edge_src, edge_dst, edge_attr,
                                           edge_scalars, fc_w1, fc_w2,
                                           offsets, slots, ACC);
  k3_stage2<<<2048, 256, 0, stream>>>(ACC, w_lin2_s, w_lin2_v, out);
}